// Round 2
// baseline (15879.288 us; speedup 1.0000x reference)
//
#include <hip/hip_runtime.h>
#include <hip/hip_bf16.h>
#include <stdint.h>

typedef __hip_bfloat16 bf16;
typedef __attribute__((ext_vector_type(8))) short short8;
typedef __attribute__((ext_vector_type(4))) float f32x4;
typedef __attribute__((ext_vector_type(4))) unsigned int u32x4;

#define NB   64
#define NT   2048
#define NV   32000
#define ND   256
#define NH4  1024
#define NCLS 27

// ---------------- dtype conversion / packing ----------------

__global__ __launch_bounds__(256) void k_cvt_embed(const float* __restrict__ e,
                                                   bf16* __restrict__ o) {
  int i = blockIdx.x * blockDim.x + threadIdx.x;   // quad index, grid sized exactly
  float4 v = reinterpret_cast<const float4*>(e)[i];
  union { bf16 h[4]; uint2 u; } pk;
  pk.h[0] = __float2bfloat16(v.x);
  pk.h[1] = __float2bfloat16(v.y);
  pk.h[2] = __float2bfloat16(v.z);
  pk.h[3] = __float2bfloat16(v.w);
  reinterpret_cast<uint2*>(o)[i] = pk.u;
}

// Wi [256][1024] f32 -> Wi_t [1024][256] bf16 (k-contiguous per output column)
__global__ __launch_bounds__(256) void k_cvt_wi(const float* __restrict__ wi,
                                                bf16* __restrict__ wit) {
  int i = blockIdx.x * blockDim.x + threadIdx.x;   // 0 .. 1024*256-1
  int col = i >> 8;
  int k   = i & 255;
  wit[i] = __float2bfloat16(wi[k * NH4 + col]);
}

// Wh [256][1024] f32 -> packed MFMA B-fragments:
// whp[((nt*8 + kg)*64 + lane)*8 + i] = Wh[kg*32 + (lane>>4)*8 + i][nt*16 + (lane&15)]
__global__ __launch_bounds__(256) void k_cvt_whp(const float* __restrict__ wh,
                                                 bf16* __restrict__ whp) {
  int idx  = blockIdx.x * blockDim.x + threadIdx.x; // 0 .. 262143
  int i    = idx & 7;
  int lane = (idx >> 3) & 63;
  int kg   = (idx >> 9) & 7;
  int nt   = idx >> 12;
  int k = kg * 32 + (lane >> 4) * 8 + i;
  int n = nt * 16 + (lane & 15);
  whp[idx] = __float2bfloat16(wh[k * NH4 + n]);
}

// ---------------- zx = embed[tokens] @ Wi for one time-chunk ----------------
// Rows r = b*CHUNK + lt (64*CHUNK rows). 64x64 tile, BK=32, 4 waves (2x2).
__global__ __launch_bounds__(256) void k_gemm_zx(const int*  __restrict__ tokens,
                                                 const bf16* __restrict__ eb,
                                                 const bf16* __restrict__ wit,
                                                 bf16* __restrict__ zx,
                                                 int t0, int lgch) {
  __shared__ bf16 As[4 * 64 * 8];
  __shared__ bf16 Bs[4 * 64 * 8];
  int bid  = blockIdx.x;
  int nb   = bid & 15;
  int mb   = bid >> 4;
  int m0   = mb * 64, n0 = nb * 64;
  int tid  = threadIdx.x, lane = tid & 63, wave = tid >> 6;
  int wm   = wave >> 1, wn = wave & 1;
  int srow = tid >> 2;            // staging row 0..63
  int skg  = tid & 3;             // staging k-group 0..3

  int r    = m0 + srow;
  int bidx = r >> lgch;                       // batch
  int lt   = r & ((1 << lgch) - 1);           // local timestep
  long trow = (long)tokens[bidx * NT + t0 + lt] * ND;
  const bf16* ap = eb  + trow + skg * 8;
  const bf16* bp = wit + (long)(n0 + srow) * ND + skg * 8;
  bf16* as_dst = &As[(skg * 64 + srow) * 8];
  bf16* bs_dst = &Bs[(skg * 64 + srow) * 8];

  f32x4 acc[2][2] = {};
  for (int k0 = 0; k0 < ND; k0 += 32) {
    __syncthreads();
    *(u32x4*)as_dst = *(const u32x4*)(ap + k0);
    *(u32x4*)bs_dst = *(const u32x4*)(bp + k0);
    __syncthreads();
    short8 a0 = *(const short8*)&As[((lane >> 4) * 64 + wm * 32 +  0 + (lane & 15)) * 8];
    short8 a1 = *(const short8*)&As[((lane >> 4) * 64 + wm * 32 + 16 + (lane & 15)) * 8];
    short8 b0 = *(const short8*)&Bs[((lane >> 4) * 64 + wn * 32 +  0 + (lane & 15)) * 8];
    short8 b1 = *(const short8*)&Bs[((lane >> 4) * 64 + wn * 32 + 16 + (lane & 15)) * 8];
    acc[0][0] = __builtin_amdgcn_mfma_f32_16x16x32_bf16(a0, b0, acc[0][0], 0, 0, 0);
    acc[0][1] = __builtin_amdgcn_mfma_f32_16x16x32_bf16(a0, b1, acc[0][1], 0, 0, 0);
    acc[1][0] = __builtin_amdgcn_mfma_f32_16x16x32_bf16(a1, b0, acc[1][0], 0, 0, 0);
    acc[1][1] = __builtin_amdgcn_mfma_f32_16x16x32_bf16(a1, b1, acc[1][1], 0, 0, 0);
  }
  int r0 = m0 + wm * 32 + (lane >> 4) * 4;
  int c0 = n0 + wn * 32 + (lane & 15);
#pragma unroll
  for (int fm = 0; fm < 2; ++fm)
#pragma unroll
    for (int fn = 0; fn < 2; ++fn)
#pragma unroll
      for (int i = 0; i < 4; ++i)
        zx[(long)(r0 + fm * 16 + i) * NH4 + (c0 + fn * 16)] =
            __float2bfloat16(acc[fm][fn][i]);
}

// ---------------- LSTM scan over one time-chunk ----------------
// 16 workgroups, each owns 4 batches (M padded 4->16), 512 threads = 8 waves.
// Wave w computes column tiles nt = w*8 .. w*8+7. h in LDS A-fragment layout,
// z exchanged via LDS, c in registers. State persisted in cst/hst (f32).
__device__ __forceinline__ float sigf(float x) {
  return __builtin_amdgcn_rcpf(1.f + __expf(-x));
}
__device__ __forceinline__ float tanh_fast(float x) {
  return 1.f - 2.f * __builtin_amdgcn_rcpf(1.f + __expf(2.f * x));
}

__global__ __launch_bounds__(512) void k_lstm(const bf16* __restrict__ zxc,
                                              const bf16* __restrict__ whp,
                                              const float* __restrict__ bh,
                                              float* __restrict__ cst,
                                              float* __restrict__ hst,
                                              int t0, int tn) {
  __shared__ bf16  hs[32 * 16 * 8];     // 8 KB, A-operand fragments
  __shared__ float zl[4][NH4 + 4];      // 16.1 KB, z exchange [batch][col]

  int g    = blockIdx.x;                // batch group: batches 4g..4g+3
  int tid  = threadIdx.x;
  int lane = tid & 63;
  int wave = tid >> 6;

  // zero h fragments (covers padded rows)
  reinterpret_cast<float4*>(hs)[tid] = make_float4(0.f, 0.f, 0.f, 0.f);

  // gate-phase identity: thread owns (j, b0) and (j, b0+1)
  int j  = tid & 255;
  int b0 = (tid >> 8) * 2;
  float c0 = 0.f, c1 = 0.f;
  float h0 = 0.f, h1 = 0.f;
  if (t0 != 0) {
    c0 = cst[(g * 4 + b0) * 256 + j];
    c1 = cst[(g * 4 + b0 + 1) * 256 + j];
    // real h rows into fragments (after the vector zero-init lands)
    __syncthreads();
    hs[((j >> 3) * 16 + b0) * 8 + (j & 7)]     = __float2bfloat16(hst[(g * 4 + b0) * 256 + j]);
    hs[((j >> 3) * 16 + b0 + 1) * 8 + (j & 7)] = __float2bfloat16(hst[(g * 4 + b0 + 1) * 256 + j]);
  }
  float bhv[4];
#pragma unroll
  for (int q = 0; q < 4; ++q) bhv[q] = bh[q * 256 + j];
  const bf16* zx0 = zxc + (long)(g * 4 + b0) * tn * NH4;
  const bf16* zx1 = zxc + (long)(g * 4 + b0 + 1) * tn * NH4;

  __syncthreads();

  for (int t = 0; t < tn; ++t) {
    // prefetch this step's zx early; consumed after the barrier
    float z0v[4], z1v[4];
#pragma unroll
    for (int q = 0; q < 4; ++q) {
      z0v[q] = __bfloat162float(zx0[(long)t * NH4 + q * 256 + j]);
      z1v[q] = __bfloat162float(zx1[(long)t * NH4 + q * 256 + j]);
    }

    // z = h @ Wh  (padded M=16, rows 0..3 real)
    f32x4 acc[8] = {};
#pragma unroll 2
    for (int k0 = 0; k0 < 8; ++k0) {
      short8 a = *(const short8*)&hs[((k0 * 4 + (lane >> 4)) * 16 + (lane & 15)) * 8];
#pragma unroll
      for (int ntl = 0; ntl < 8; ++ntl) {
        int nt = wave * 8 + ntl;
        short8 bw = *(const short8*)&whp[((long)(nt * 8 + k0) * 64 + lane) * 8];
        acc[ntl] = __builtin_amdgcn_mfma_f32_16x16x32_bf16(a, bw, acc[ntl], 0, 0, 0);
      }
    }
    // write real rows (batches 0..3 live in lanes 0..15, regs i=0..3)
    if ((lane >> 4) == 0) {
#pragma unroll
      for (int ntl = 0; ntl < 8; ++ntl) {
        int col = (wave * 8 + ntl) * 16 + (lane & 15);
#pragma unroll
        for (int i = 0; i < 4; ++i) zl[i][col] = acc[ntl][i];
      }
    }
    __syncthreads();

    // gates for (b0, j) and (b0+1, j)
    {
      float zi = zl[b0][j]       + z0v[0] + bhv[0];
      float zf = zl[b0][256 + j] + z0v[1] + bhv[1];
      float zg = zl[b0][512 + j] + z0v[2] + bhv[2];
      float zo = zl[b0][768 + j] + z0v[3] + bhv[3];
      c0 = sigf(zf) * c0 + sigf(zi) * tanh_fast(zg);
      h0 = sigf(zo) * tanh_fast(c0);

      float yi = zl[b0 + 1][j]       + z1v[0] + bhv[0];
      float yf = zl[b0 + 1][256 + j] + z1v[1] + bhv[1];
      float yg = zl[b0 + 1][512 + j] + z1v[2] + bhv[2];
      float yo = zl[b0 + 1][768 + j] + z1v[3] + bhv[3];
      c1 = sigf(yf) * c1 + sigf(yi) * tanh_fast(yg);
      h1 = sigf(yo) * tanh_fast(c1);

      hs[((j >> 3) * 16 + b0) * 8 + (j & 7)]     = __float2bfloat16(h0);
      hs[((j >> 3) * 16 + b0 + 1) * 8 + (j & 7)] = __float2bfloat16(h1);
    }
    __syncthreads();
  }

  // persist state for next chunk (hst doubles as final-h for k_out)
  cst[(g * 4 + b0) * 256 + j]     = c0;
  cst[(g * 4 + b0 + 1) * 256 + j] = c1;
  hst[(g * 4 + b0) * 256 + j]     = h0;
  hst[(g * 4 + b0 + 1) * 256 + j] = h1;
}

// ---------------- y = h @ Wo + bo ----------------
__global__ __launch_bounds__(64) void k_out(const float* __restrict__ hfin,
                                            const float* __restrict__ wo,
                                            const float* __restrict__ bo,
                                            float* __restrict__ y) {
  __shared__ float hsm[256];
  int b = blockIdx.x, tid = threadIdx.x;
  for (int i = tid; i < 256; i += 64) hsm[i] = hfin[b * 256 + i];
  __syncthreads();
  if (tid < NCLS) {
    float s = bo[tid];
    for (int k = 0; k < 256; ++k) s += hsm[k] * wo[k * NCLS + tid];
    y[b * NCLS + tid] = s;
  }
}

// ---------------- launcher ----------------
extern "C" void kernel_launch(void* const* d_in, const int* in_sizes, int n_in,
                              void* d_out, int out_size, void* d_ws, size_t ws_size,
                              hipStream_t stream) {
  const int*   tokens = (const int*)d_in[0];
  const float* embed  = (const float*)d_in[3];
  const float* wi     = (const float*)d_in[4];
  const float* wh     = (const float*)d_in[5];
  const float* bh     = (const float*)d_in[6];
  const float* wo     = (const float*)d_in[7];
  const float* bo     = (const float*)d_in[8];
  float* y = (float*)d_out;

  char* ws = (char*)d_ws;
  bf16* eb    = (bf16*)ws;  ws += (size_t)NV * ND * 2;        // 16.38 MB
  bf16* wit   = (bf16*)ws;  ws += (size_t)NH4 * ND * 2;       // 0.5 MB
  bf16* whp   = (bf16*)ws;  ws += (size_t)ND * NH4 * 2;       // 0.5 MB
  float* cst  = (float*)ws; ws += (size_t)NB * ND * 4;        // 64 KB
  float* hst  = (float*)ws; ws += (size_t)NB * ND * 4;        // 64 KB
  size_t fixed = (size_t)(ws - (char*)d_ws);
  bf16* zxc = (bf16*)ws;                                      // chunk buffer

  // pick largest power-of-two chunk whose zx buffer fits the workspace
  int CHUNK = 32, lgch = 5;
  static const int cand[]  = {2048, 512, 256, 128, 64, 32};
  static const int candl[] = {11, 9, 8, 7, 6, 5};
  for (int ci = 0; ci < 6; ++ci) {
    size_t need = fixed + (size_t)NB * cand[ci] * NH4 * 2;
    if (need <= ws_size) { CHUNK = cand[ci]; lgch = candl[ci]; break; }
  }

  hipLaunchKernelGGL(k_cvt_embed, dim3(NV * ND / 4 / 256), dim3(256), 0, stream, embed, eb);
  hipLaunchKernelGGL(k_cvt_wi,    dim3(NH4 * ND / 256), dim3(256), 0, stream, wi, wit);
  hipLaunchKernelGGL(k_cvt_whp,   dim3(ND * NH4 / 256), dim3(256), 0, stream, wh, whp);

  for (int t0 = 0; t0 < NT; t0 += CHUNK) {
    hipLaunchKernelGGL(k_gemm_zx, dim3(CHUNK * 16), dim3(256), 0, stream,
                       tokens, eb, wit, zxc, t0, lgch);
    hipLaunchKernelGGL(k_lstm, dim3(16), dim3(512), 0, stream,
                       zxc, whp, bh, cst, hst, t0, CHUNK);
  }
  hipLaunchKernelGGL(k_out, dim3(NB), dim3(64), 0, stream, hst, wo, bo, y);
}

// Round 3
// 7709.178 us; speedup vs baseline: 2.0598x; 2.0598x over previous
//
#include <hip/hip_runtime.h>
#include <hip/hip_bf16.h>
#include <stdint.h>

typedef __hip_bfloat16 bf16;
typedef __attribute__((ext_vector_type(8))) short short8;
typedef __attribute__((ext_vector_type(4))) float f32x4;
typedef __attribute__((ext_vector_type(4))) unsigned int u32x4;

#define NB   64
#define NT   2048
#define NV   32000
#define ND   256
#define NH4  1024
#define NCLS 27
#define NWG  16
#define HBUF_ELEMS (4 * 8 * 64 * 8)   // [mt][k0][lane][8] bf16, one parity

// ---------------- dtype conversion / packing ----------------

__global__ __launch_bounds__(256) void k_cvt_embed(const float* __restrict__ e,
                                                   bf16* __restrict__ o) {
  int i = blockIdx.x * blockDim.x + threadIdx.x;   // quad index, grid sized exactly
  float4 v = reinterpret_cast<const float4*>(e)[i];
  union { bf16 h[4]; uint2 u; } pk;
  pk.h[0] = __float2bfloat16(v.x);
  pk.h[1] = __float2bfloat16(v.y);
  pk.h[2] = __float2bfloat16(v.z);
  pk.h[3] = __float2bfloat16(v.w);
  reinterpret_cast<uint2*>(o)[i] = pk.u;
}

// Wi [256][1024] f32 -> Wi_t [1024][256] bf16 (k-contiguous per output column)
__global__ __launch_bounds__(256) void k_cvt_wi(const float* __restrict__ wi,
                                                bf16* __restrict__ wit) {
  int i = blockIdx.x * blockDim.x + threadIdx.x;   // 0 .. 1024*256-1
  int col = i >> 8;
  int k   = i & 255;
  wit[i] = __float2bfloat16(wi[k * NH4 + col]);
}

// Wh [256][1024] f32 -> packed MFMA B-fragments:
// whp[((nt*8 + kg)*64 + lane)*8 + i] = Wh[kg*32 + (lane>>4)*8 + i][nt*16 + (lane&15)]
__global__ __launch_bounds__(256) void k_cvt_whp(const float* __restrict__ wh,
                                                 bf16* __restrict__ whp) {
  int idx  = blockIdx.x * blockDim.x + threadIdx.x; // 0 .. 262143
  int i    = idx & 7;
  int lane = (idx >> 3) & 63;
  int kg   = (idx >> 9) & 7;
  int nt   = idx >> 12;
  int k = kg * 32 + (lane >> 4) * 8 + i;
  int n = nt * 16 + (lane & 15);
  whp[idx] = __float2bfloat16(wh[k * NH4 + n]);
}

// zero h ping-pong buffer + flag array (every launch -> replay-deterministic)
__global__ __launch_bounds__(256) void k_init(bf16* __restrict__ hbuf,
                                              unsigned* __restrict__ fl) {
  int i = blockIdx.x * blockDim.x + threadIdx.x;
  if (i < 2 * HBUF_ELEMS / 2) reinterpret_cast<uint*>(hbuf)[i] = 0u;  // 2 bf16/word
  if (i < NT + 2) fl[i] = 0u;
}

// ---------------- zx = embed[tokens] @ Wi for one time-chunk ----------------
__global__ __launch_bounds__(256) void k_gemm_zx(const int*  __restrict__ tokens,
                                                 const bf16* __restrict__ eb,
                                                 const bf16* __restrict__ wit,
                                                 bf16* __restrict__ zx,
                                                 int t0, int lgch) {
  __shared__ bf16 As[4 * 64 * 8];
  __shared__ bf16 Bs[4 * 64 * 8];
  int bid  = blockIdx.x;
  int nb   = bid & 15;
  int mb   = bid >> 4;
  int m0   = mb * 64, n0 = nb * 64;
  int tid  = threadIdx.x, lane = tid & 63, wave = tid >> 6;
  int wm   = wave >> 1, wn = wave & 1;
  int srow = tid >> 2;
  int skg  = tid & 3;

  int r    = m0 + srow;
  int bidx = r >> lgch;
  int lt   = r & ((1 << lgch) - 1);
  long trow = (long)tokens[bidx * NT + t0 + lt] * ND;
  const bf16* ap = eb  + trow + skg * 8;
  const bf16* bp = wit + (long)(n0 + srow) * ND + skg * 8;
  bf16* as_dst = &As[(skg * 64 + srow) * 8];
  bf16* bs_dst = &Bs[(skg * 64 + srow) * 8];

  f32x4 acc[2][2] = {};
  for (int k0 = 0; k0 < ND; k0 += 32) {
    __syncthreads();
    *(u32x4*)as_dst = *(const u32x4*)(ap + k0);
    *(u32x4*)bs_dst = *(const u32x4*)(bp + k0);
    __syncthreads();
    short8 a0 = *(const short8*)&As[((lane >> 4) * 64 + wm * 32 +  0 + (lane & 15)) * 8];
    short8 a1 = *(const short8*)&As[((lane >> 4) * 64 + wm * 32 + 16 + (lane & 15)) * 8];
    short8 b0 = *(const short8*)&Bs[((lane >> 4) * 64 + wn * 32 +  0 + (lane & 15)) * 8];
    short8 b1 = *(const short8*)&Bs[((lane >> 4) * 64 + wn * 32 + 16 + (lane & 15)) * 8];
    acc[0][0] = __builtin_amdgcn_mfma_f32_16x16x32_bf16(a0, b0, acc[0][0], 0, 0, 0);
    acc[0][1] = __builtin_amdgcn_mfma_f32_16x16x32_bf16(a0, b1, acc[0][1], 0, 0, 0);
    acc[1][0] = __builtin_amdgcn_mfma_f32_16x16x32_bf16(a1, b0, acc[1][0], 0, 0, 0);
    acc[1][1] = __builtin_amdgcn_mfma_f32_16x16x32_bf16(a1, b1, acc[1][1], 0, 0, 0);
  }
  int r0 = m0 + wm * 32 + (lane >> 4) * 4;
  int c0 = n0 + wn * 32 + (lane & 15);
#pragma unroll
  for (int fm = 0; fm < 2; ++fm)
#pragma unroll
    for (int fn = 0; fn < 2; ++fn)
#pragma unroll
      for (int i = 0; i < 4; ++i)
        zx[(long)(r0 + fm * 16 + i) * NH4 + (c0 + fn * 16)] =
            __float2bfloat16(acc[fm][fn][i]);
}

// ---------------- LSTM scan, column-split ----------------
// 16 WGs x 256 threads (4 waves). WG g owns hidden units U in [16g, 16g+16)
// for ALL 64 batches. Wave w owns batch m-tile w (16 batches) x all 4 gate
// tiles. Wh slice register-resident (bw[4][8] = 128 VGPR). h exchanged via
// global ping-pong buffer in A-fragment layout + per-step flag sync.
__device__ __forceinline__ float sigf(float x) {
  return __builtin_amdgcn_rcpf(1.f + __expf(-x));
}
__device__ __forceinline__ float tanh_fast(float x) {
  return 1.f - 2.f * __builtin_amdgcn_rcpf(1.f + __expf(2.f * x));
}

__global__ __launch_bounds__(256, 1) void k_lstm(const bf16* __restrict__ zxc,
                                                 const bf16* __restrict__ whp,
                                                 const float* __restrict__ bh,
                                                 float* __restrict__ cst,
                                                 float* __restrict__ hst,
                                                 bf16* __restrict__ hbuf,
                                                 unsigned* __restrict__ fl,
                                                 int t0, int tn) {
  int g    = blockIdx.x;          // 0..15
  int tid  = threadIdx.x;
  int lane = tid & 63;
  int w    = tid >> 6;            // wave = m-tile
  int u    = lane & 15;           // unit within WG
  int U    = g * 16 + u;          // global hidden unit
  int rq   = lane >> 4;           // row quad 0..3

  // register-resident Wh B-fragments: gate q, k-tile k0
  short8 bw[4][8];
#pragma unroll
  for (int q = 0; q < 4; ++q) {
    int nt = q * 16 + g;
#pragma unroll
    for (int k0 = 0; k0 < 8; ++k0)
      bw[q][k0] = *(const short8*)&whp[((long)(nt * 8 + k0) * 64 + lane) * 8];
  }
  float bhv[4];
#pragma unroll
  for (int q = 0; q < 4; ++q) bhv[q] = bh[q * 256 + U];

  float c[4];
#pragma unroll
  for (int i = 0; i < 4; ++i) c[i] = 0.f;
  if (t0 != 0) {
#pragma unroll
    for (int i = 0; i < 4; ++i) c[i] = cst[(w * 16 + rq * 4 + i) * 256 + U];
  }

  // h-write addressing for this thread (constant parts)
  int kw = g >> 1;                              // k0 of this WG's units
  int lane_hi = ((U >> 3) & 3) << 4;            // bits 4..5 of dest lane
  int elo = u & 7;                              // element within 8

  for (int lt = 0; lt < tn; ++lt) {
    int t = t0 + lt;
    // prefetch zx for this step BEFORE the spin (independent of h)
    float zxv[4][4];
#pragma unroll
    for (int q = 0; q < 4; ++q)
#pragma unroll
      for (int i = 0; i < 4; ++i)
        zxv[q][i] = __bfloat162float(
            zxc[((long)(w * 16 + rq * 4 + i) * tn + lt) * NH4 + q * 256 + U]);

    // wait for h(t) from all 16 producers
    if (t > 0) {
      if (tid == 0) {
        while (__hip_atomic_load(&fl[t], __ATOMIC_ACQUIRE,
                                 __HIP_MEMORY_SCOPE_AGENT) < (unsigned)NWG) {}
      }
    }
    __syncthreads();

    // A-fragments of h(t) for m-tile w
    const bf16* hb = hbuf + (size_t)(t & 1) * HBUF_ELEMS;
    short8 a[8];
#pragma unroll
    for (int k0 = 0; k0 < 8; ++k0)
      a[k0] = *(const short8*)&hb[((w * 8 + k0) * 64 + lane) * 8];

    f32x4 acc[4] = {};
#pragma unroll
    for (int k0 = 0; k0 < 8; ++k0) {
#pragma unroll
      for (int q = 0; q < 4; ++q)
        acc[q] = __builtin_amdgcn_mfma_f32_16x16x32_bf16(a[k0], bw[q][k0], acc[q], 0, 0, 0);
    }

    // gates: thread holds all 4 gates for its 4 batches (i = acc reg index)
    bf16* hbn = hbuf + (size_t)((t + 1) & 1) * HBUF_ELEMS;
#pragma unroll
    for (int i = 0; i < 4; ++i) {
      float zi = acc[0][i] + zxv[0][i] + bhv[0];
      float zf = acc[1][i] + zxv[1][i] + bhv[1];
      float zg = acc[2][i] + zxv[2][i] + bhv[2];
      float zo = acc[3][i] + zxv[3][i] + bhv[3];
      c[i] = sigf(zf) * c[i] + sigf(zi) * tanh_fast(zg);
      float h = sigf(zo) * tanh_fast(c[i]);
      int b = w * 16 + rq * 4 + i;
      int lane_dst = (b & 15) | lane_hi;
      hbn[((w * 8 + kw) * 64 + lane_dst) * 8 + elo] = __float2bfloat16(h);
      if (t == NT - 1) hst[b * 256 + U] = h;
    }

    // publish h(t+1): drain stores (syncthreads waits vmcnt) then release
    __syncthreads();
    if (tid == 0)
      __hip_atomic_fetch_add(&fl[t + 1], 1u, __ATOMIC_RELEASE,
                             __HIP_MEMORY_SCOPE_AGENT);
  }

#pragma unroll
  for (int i = 0; i < 4; ++i)
    cst[(w * 16 + rq * 4 + i) * 256 + U] = c[i];
}

// ---------------- y = h @ Wo + bo ----------------
__global__ __launch_bounds__(64) void k_out(const float* __restrict__ hfin,
                                            const float* __restrict__ wo,
                                            const float* __restrict__ bo,
                                            float* __restrict__ y) {
  __shared__ float hsm[256];
  int b = blockIdx.x, tid = threadIdx.x;
  for (int i = tid; i < 256; i += 64) hsm[i] = hfin[b * 256 + i];
  __syncthreads();
  if (tid < NCLS) {
    float s = bo[tid];
    for (int k = 0; k < 256; ++k) s += hsm[k] * wo[k * NCLS + tid];
    y[b * NCLS + tid] = s;
  }
}

// ---------------- launcher ----------------
extern "C" void kernel_launch(void* const* d_in, const int* in_sizes, int n_in,
                              void* d_out, int out_size, void* d_ws, size_t ws_size,
                              hipStream_t stream) {
  const int*   tokens = (const int*)d_in[0];
  const float* embed  = (const float*)d_in[3];
  const float* wi     = (const float*)d_in[4];
  const float* wh     = (const float*)d_in[5];
  const float* bh     = (const float*)d_in[6];
  const float* wo     = (const float*)d_in[7];
  const float* bo     = (const float*)d_in[8];
  float* y = (float*)d_out;

  char* ws = (char*)d_ws;
  bf16* eb     = (bf16*)ws;     ws += (size_t)NV * ND * 2;        // 16.38 MB
  bf16* wit    = (bf16*)ws;     ws += (size_t)NH4 * ND * 2;       // 0.5 MB
  bf16* whp    = (bf16*)ws;     ws += (size_t)ND * NH4 * 2;       // 0.5 MB
  float* cst   = (float*)ws;    ws += (size_t)NB * ND * 4;        // 64 KB
  float* hst   = (float*)ws;    ws += (size_t)NB * ND * 4;        // 64 KB
  bf16* hbuf   = (bf16*)ws;     ws += (size_t)2 * HBUF_ELEMS * 2; // 64 KB
  unsigned* fl = (unsigned*)ws; ws += (size_t)(NT + 2) * 4;       // 8.2 KB
  size_t fixed = (size_t)(ws - (char*)d_ws);
  bf16* zxc = (bf16*)ws;                                          // chunk buffer

  int CHUNK = 32, lgch = 5;
  static const int cand[]  = {2048, 512, 256, 128, 64, 32};
  static const int candl[] = {11, 9, 8, 7, 6, 5};
  for (int ci = 0; ci < 6; ++ci) {
    size_t need = fixed + (size_t)NB * cand[ci] * NH4 * 2;
    if (need <= ws_size) { CHUNK = cand[ci]; lgch = candl[ci]; break; }
  }

  hipLaunchKernelGGL(k_cvt_embed, dim3(NV * ND / 4 / 256), dim3(256), 0, stream, embed, eb);
  hipLaunchKernelGGL(k_cvt_wi,    dim3(NH4 * ND / 256), dim3(256), 0, stream, wi, wit);
  hipLaunchKernelGGL(k_cvt_whp,   dim3(ND * NH4 / 256), dim3(256), 0, stream, wh, whp);
  hipLaunchKernelGGL(k_init,      dim3(65), dim3(256), 0, stream, hbuf, fl);

  for (int t0 = 0; t0 < NT; t0 += CHUNK) {
    hipLaunchKernelGGL(k_gemm_zx, dim3(CHUNK * 16), dim3(256), 0, stream,
                       tokens, eb, wit, zxc, t0, lgch);
    hipLaunchKernelGGL(k_lstm, dim3(NWG), dim3(256), 0, stream,
                       zxc, whp, bh, cst, hst, hbuf, fl, t0, CHUNK);
  }
  hipLaunchKernelGGL(k_out, dim3(NB), dim3(64), 0, stream, hst, wo, bo, y);
}

// Round 5
// 5248.192 us; speedup vs baseline: 3.0257x; 1.4689x over previous
//
#include <hip/hip_runtime.h>
#include <hip/hip_bf16.h>
#include <stdint.h>

typedef __hip_bfloat16 bf16;
typedef __attribute__((ext_vector_type(8))) short short8;
typedef __attribute__((ext_vector_type(4))) float f32x4;
typedef __attribute__((ext_vector_type(4))) unsigned int u32x4;

#define NB   64
#define NT   2048
#define NV   32000
#define ND   256
#define NH4  1024
#define NCLS 27
#define POIS 0x7F807F80u

// ---------------- dtype conversion / packing ----------------

__global__ __launch_bounds__(256) void k_cvt_embed(const float* __restrict__ e,
                                                   bf16* __restrict__ o) {
  int i = blockIdx.x * blockDim.x + threadIdx.x;
  float4 v = reinterpret_cast<const float4*>(e)[i];
  union { bf16 h[4]; uint2 u; } pk;
  pk.h[0] = __float2bfloat16(v.x);
  pk.h[1] = __float2bfloat16(v.y);
  pk.h[2] = __float2bfloat16(v.z);
  pk.h[3] = __float2bfloat16(v.w);
  reinterpret_cast<uint2*>(o)[i] = pk.u;
}

// Wi [256][1024] f32 -> Wi_t [1024][256] bf16
__global__ __launch_bounds__(256) void k_cvt_wi(const float* __restrict__ wi,
                                                bf16* __restrict__ wit) {
  int i = blockIdx.x * blockDim.x + threadIdx.x;
  int col = i >> 8;
  int k   = i & 255;
  wit[i] = __float2bfloat16(wi[k * NH4 + col]);
}

// Wh [256][1024] f32 -> packed MFMA B-fragments
__global__ __launch_bounds__(256) void k_cvt_whp(const float* __restrict__ wh,
                                                 bf16* __restrict__ whp) {
  int idx  = blockIdx.x * blockDim.x + threadIdx.x;
  int i    = idx & 7;
  int lane = (idx >> 3) & 63;
  int kg   = (idx >> 9) & 7;
  int nt   = idx >> 12;
  int k = kg * 32 + (lane >> 4) * 8 + i;
  int n = nt * 16 + (lane & 15);
  whp[idx] = __float2bfloat16(wh[k * NH4 + n]);
}

// poison h slots 1..tn (each chunk, before k_lstm) -> replay-deterministic
__global__ __launch_bounds__(256) void k_poison(unsigned* __restrict__ hb, int ndw) {
  int i = blockIdx.x * blockDim.x + threadIdx.x;
  if (i < ndw) hb[8192 + i] = POIS;   // slot 0 skipped (comes from hst)
}

// ---------------- zx = embed[tokens] @ Wi, written PERMUTED ----------------
// zxp byte addr for (b, lt, col): lt*131072 + g*8192 + w*2048 + rq*512 + i*128
//   + u*8 + q*2   where col=q*256+g*16+u, b=w*16+rq*4+i. Scan thread (g,w,rq,u)
// then reads 4 x 8B contiguous per step.
__global__ __launch_bounds__(256) void k_gemm_zx(const int*  __restrict__ tokens,
                                                 const bf16* __restrict__ eb,
                                                 const bf16* __restrict__ wit,
                                                 char* __restrict__ zxp,
                                                 int t0, int lgch) {
  __shared__ bf16 As[4 * 64 * 8];
  __shared__ bf16 Bs[4 * 64 * 8];
  int bid  = blockIdx.x;
  int nb   = bid & 15;
  int mb   = bid >> 4;
  int m0   = mb * 64, n0 = nb * 64;
  int tid  = threadIdx.x, lane = tid & 63, wave = tid >> 6;
  int wm   = wave >> 1, wn = wave & 1;
  int srow = tid >> 2;
  int skg  = tid & 3;

  int r    = m0 + srow;
  int bidx = r >> lgch;
  int lt   = r & ((1 << lgch) - 1);
  long trow = (long)tokens[bidx * NT + t0 + lt] * ND;
  const bf16* ap = eb  + trow + skg * 8;
  const bf16* bp = wit + (long)(n0 + srow) * ND + skg * 8;
  bf16* as_dst = &As[(skg * 64 + srow) * 8];
  bf16* bs_dst = &Bs[(skg * 64 + srow) * 8];

  f32x4 acc[2][2] = {};
  for (int k0 = 0; k0 < ND; k0 += 32) {
    __syncthreads();
    *(u32x4*)as_dst = *(const u32x4*)(ap + k0);
    *(u32x4*)bs_dst = *(const u32x4*)(bp + k0);
    __syncthreads();
    short8 a0 = *(const short8*)&As[((lane >> 4) * 64 + wm * 32 +  0 + (lane & 15)) * 8];
    short8 a1 = *(const short8*)&As[((lane >> 4) * 64 + wm * 32 + 16 + (lane & 15)) * 8];
    short8 b0 = *(const short8*)&Bs[((lane >> 4) * 64 + wn * 32 +  0 + (lane & 15)) * 8];
    short8 b1 = *(const short8*)&Bs[((lane >> 4) * 64 + wn * 32 + 16 + (lane & 15)) * 8];
    acc[0][0] = __builtin_amdgcn_mfma_f32_16x16x32_bf16(a0, b0, acc[0][0], 0, 0, 0);
    acc[0][1] = __builtin_amdgcn_mfma_f32_16x16x32_bf16(a0, b1, acc[0][1], 0, 0, 0);
    acc[1][0] = __builtin_amdgcn_mfma_f32_16x16x32_bf16(a1, b0, acc[1][0], 0, 0, 0);
    acc[1][1] = __builtin_amdgcn_mfma_f32_16x16x32_bf16(a1, b1, acc[1][1], 0, 0, 0);
  }
  int r_base = m0 + wm * 32 + (lane >> 4) * 4;
  int c_base = n0 + wn * 32 + (lane & 15);
  int mask = (1 << lgch) - 1;
#pragma unroll
  for (int fm = 0; fm < 2; ++fm)
#pragma unroll
    for (int fn = 0; fn < 2; ++fn)
#pragma unroll
      for (int i2 = 0; i2 < 4; ++i2) {
        int rr  = r_base + fm * 16 + i2;
        int col = c_base + fn * 16;
        int b   = rr >> lgch, lt2 = rr & mask;
        int q   = col >> 8, gg = (col >> 4) & 15, uu = col & 15;
        int w_  = b >> 4, rq_ = (b >> 2) & 3, ii = b & 3;
        size_t off = (size_t)lt2 * 131072 + gg * 8192 + w_ * 2048 + rq_ * 512 +
                     ii * 128 + uu * 8 + q * 2;
        *(bf16*)(zxp + off) = __float2bfloat16(acc[fm][fn][i2]);
      }
}

// ---------------- LSTM scan, flagless data-poll ----------------
// 64 single-wave WGs: wid -> (g = unit-group of 16, w = batch m-tile of 16).
// Wh slice register-resident (bw[4][8] = 128 VGPR). h(t0+s) lives in
// hbuf slot s (natural [b][u] bf16 layout); producers publish via relaxed
// agent atomic dword stores, consumers poll u64 loads against bf16-inf poison
// and consume the polled values directly (per-location coherence, no fences).
__device__ __forceinline__ float sigf(float x) {
  return __builtin_amdgcn_rcpf(1.f + __expf(-x));
}
__device__ __forceinline__ float tanh_fast(float x) {
  return 1.f - 2.f * __builtin_amdgcn_rcpf(1.f + __expf(2.f * x));
}
__device__ __forceinline__ unsigned short f2b(float x) {
  bf16 t = __float2bfloat16(x);
  return *reinterpret_cast<unsigned short*>(&t);
}

union Frag { unsigned long long q[2]; short8 s; };

__global__ __launch_bounds__(64, 1) void k_lstm(const char* __restrict__ zxp,
                                                const bf16* __restrict__ whp,
                                                const float* __restrict__ bh,
                                                float* __restrict__ cst,
                                                float* __restrict__ hst,
                                                unsigned* __restrict__ hbuf,
                                                int t0, int tn) {
  int wid = blockIdx.x;
  int g   = wid & 15;          // unit group: units [16g, 16g+16)
  int w   = wid >> 4;          // batch m-tile: batches [16w, 16w+16)
  int l   = threadIdx.x;
  int l15 = l & 15, l4 = l >> 4;

  // register-resident Wh B-fragments
  short8 bw[4][8];
#pragma unroll
  for (int q = 0; q < 4; ++q) {
    int nt = q * 16 + g;
#pragma unroll
    for (int k0 = 0; k0 < 8; ++k0)
      bw[q][k0] = *(const short8*)&whp[((long)(nt * 8 + k0) * 64 + l) * 8];
  }
  int U = g * 16 + l15;        // gate-phase unit
  float bhv[4];
#pragma unroll
  for (int q = 0; q < 4; ++q) bhv[q] = bh[q * 256 + U];

  float c[4];
#pragma unroll
  for (int i = 0; i < 4; ++i)
    c[i] = (t0 == 0) ? 0.f : cst[(w * 16 + l4 * 4 + i) * 256 + U];

  // initial A-fragments of h(t0): zeros or hst (kernel-boundary visible)
  short8 a[8];
  if (t0 == 0) {
#pragma unroll
    for (int k0 = 0; k0 < 8; ++k0) a[k0] = (short8)(short)0;
  } else {
    int rowb = w * 16 + l15;
#pragma unroll
    for (int k0 = 0; k0 < 8; ++k0) {
      const float* hp = &hst[rowb * 256 + l4 * 8 + k0 * 32];
      float4 f0 = *(const float4*)hp;
      float4 f1 = *(const float4*)(hp + 4);
      unsigned short e[8] = {f2b(f0.x), f2b(f0.y), f2b(f0.z), f2b(f0.w),
                             f2b(f1.x), f2b(f1.y), f2b(f1.z), f2b(f1.w)};
      a[k0] = *(const short8*)e;
    }
  }

  const char* zbase = zxp + g * 8192 + w * 2048 + l4 * 512 + l15 * 8;
  unsigned long long* hb64 = (unsigned long long*)hbuf;

  // zx prefetch for step 0
  uint2 z0[4], z1[4];
#pragma unroll
  for (int i = 0; i < 4; ++i) z0[i] = *(const uint2*)(zbase + i * 128);

  int pollb = (w * 16 + l15) * 64 + l4 * 2;   // u64 base within a slot row-block

  for (int lt = 0; lt < tn; ++lt) {
    // prefetch next step's zx (hidden under poll + compute)
    if (lt + 1 < tn) {
#pragma unroll
      for (int i = 0; i < 4; ++i)
        z1[i] = *(const uint2*)(zbase + (size_t)(lt + 1) * 131072 + i * 128);
    }

    // poll h(t0+lt) for lt>0 (slot lt), consume polled values directly.
    // Bounded spin: legit waits are tens of iters; 65536 means a visibility
    // bug -> break with wrong data (diagnosable) instead of a 600s hang.
    if (lt > 0) {
      unsigned long long* sb = hb64 + (size_t)lt * 4096;  // 32KB slot /8
      Frag fr[8];
      for (unsigned spin = 0; spin < 65536u; ++spin) {
#pragma unroll
        for (int k0 = 0; k0 < 8; ++k0) {
          fr[k0].q[0] = __hip_atomic_load(sb + pollb + k0 * 8,
                                          __ATOMIC_RELAXED, __HIP_MEMORY_SCOPE_AGENT);
          fr[k0].q[1] = __hip_atomic_load(sb + pollb + k0 * 8 + 1,
                                          __ATOMIC_RELAXED, __HIP_MEMORY_SCOPE_AGENT);
        }
        bool bad = false;
#pragma unroll
        for (int k0 = 0; k0 < 8; ++k0) {
          unsigned long long q0 = fr[k0].q[0], q1 = fr[k0].q[1];
          bad |= ((unsigned)q0 == POIS) | ((unsigned)(q0 >> 32) == POIS) |
                 ((unsigned)q1 == POIS) | ((unsigned)(q1 >> 32) == POIS);
        }
        if (!__any(bad)) break;
      }
#pragma unroll
      for (int k0 = 0; k0 < 8; ++k0) a[k0] = fr[k0].s;
    }

    // z = h @ Wh
    f32x4 acc[4] = {};
#pragma unroll
    for (int k0 = 0; k0 < 8; ++k0) {
#pragma unroll
      for (int q = 0; q < 4; ++q)
        acc[q] = __builtin_amdgcn_mfma_f32_16x16x32_bf16(a[k0], bw[q][k0], acc[q], 0, 0, 0);
    }

    // gates: thread owns (4 batches x 1 unit); zx packed as 4 x (q0..q3)
    unsigned my[4];
    float hv[4];
#pragma unroll
    for (int i = 0; i < 4; ++i) {
      float zi = acc[0][i] + __uint_as_float((z0[i].x & 0xFFFFu) << 16) + bhv[0];
      float zf = acc[1][i] + __uint_as_float((z0[i].x >> 16) << 16)     + bhv[1];
      float zg = acc[2][i] + __uint_as_float((z0[i].y & 0xFFFFu) << 16) + bhv[2];
      float zo = acc[3][i] + __uint_as_float((z0[i].y >> 16) << 16)     + bhv[3];
      c[i] = sigf(zf) * c[i] + sigf(zi) * tanh_fast(zg);
      hv[i] = sigf(zo) * tanh_fast(c[i]);
      my[i] = f2b(hv[i]);
    }

    // publish h(t+1) into slot lt+1: pack unit-pairs cross-lane, 2 dword stores
    unsigned pt[4];
#pragma unroll
    for (int i = 0; i < 4; ++i) pt[i] = (unsigned)__shfl_xor((int)my[i], 1, 64);
    bool even = ((l & 1) == 0);
    int i0 = even ? 0 : 2;
#pragma unroll
    for (int k = 0; k < 2; ++k) {
      int i = i0 + k;
      unsigned dw = even ? (my[i] | (pt[i] << 16)) : (pt[i] | (my[i] << 16));
      int b = w * 16 + l4 * 4 + i;
      // dword index within row = global unit pair = g*8 + (l15>>1)
      // (R4 bug: the g*8 term was missing -> units 16..255 never written -> hang)
      unsigned* p = hbuf + ((size_t)(lt + 1) * 64 + b) * 128 + g * 8 + (l15 >> 1);
      __hip_atomic_store(p, dw, __ATOMIC_RELAXED, __HIP_MEMORY_SCOPE_AGENT);
    }

    if (lt == tn - 1) {
#pragma unroll
      for (int i = 0; i < 4; ++i)
        hst[(w * 16 + l4 * 4 + i) * 256 + U] = hv[i];
    }

#pragma unroll
    for (int i = 0; i < 4; ++i) z0[i] = z1[i];
  }

#pragma unroll
  for (int i = 0; i < 4; ++i)
    cst[(w * 16 + l4 * 4 + i) * 256 + U] = c[i];
}

// ---------------- y = h @ Wo + bo ----------------
__global__ __launch_bounds__(64) void k_out(const float* __restrict__ hfin,
                                            const float* __restrict__ wo,
                                            const float* __restrict__ bo,
                                            float* __restrict__ y) {
  __shared__ float hsm[256];
  int b = blockIdx.x, tid = threadIdx.x;
  for (int i = tid; i < 256; i += 64) hsm[i] = hfin[b * 256 + i];
  __syncthreads();
  if (tid < NCLS) {
    float s = bo[tid];
    for (int k = 0; k < 256; ++k) s += hsm[k] * wo[k * NCLS + tid];
    y[b * NCLS + tid] = s;
  }
}

// ---------------- launcher ----------------
extern "C" void kernel_launch(void* const* d_in, const int* in_sizes, int n_in,
                              void* d_out, int out_size, void* d_ws, size_t ws_size,
                              hipStream_t stream) {
  const int*   tokens = (const int*)d_in[0];
  const float* embed  = (const float*)d_in[3];
  const float* wi     = (const float*)d_in[4];
  const float* wh     = (const float*)d_in[5];
  const float* bh     = (const float*)d_in[6];
  const float* wo     = (const float*)d_in[7];
  const float* bo     = (const float*)d_in[8];
  float* y = (float*)d_out;

  char* ws = (char*)d_ws;
  bf16* eb     = (bf16*)ws;     ws += (size_t)NV * ND * 2;        // 16.38 MB
  bf16* wit    = (bf16*)ws;     ws += (size_t)NH4 * ND * 2;       // 0.5 MB
  bf16* whp    = (bf16*)ws;     ws += (size_t)ND * NH4 * 2;       // 0.5 MB
  float* cst   = (float*)ws;    ws += (size_t)NB * ND * 4;        // 64 KB
  float* hst   = (float*)ws;    ws += (size_t)NB * ND * 4;        // 64 KB
  size_t fixed = (size_t)(ws - (char*)d_ws);

  // pick largest chunk: need = fixed + hbuf((ch+1)*32KB) + zxp(ch*128KB)
  int CHUNK = 32, lgch = 5;
  static const int cand[]  = {2048, 1024, 512, 256, 128, 64, 32};
  static const int candl[] = {11, 10, 9, 8, 7, 6, 5};
  for (int ci = 0; ci < 7; ++ci) {
    size_t need = fixed + (size_t)(cand[ci] + 1) * 32768 + (size_t)cand[ci] * 131072;
    if (need <= ws_size) { CHUNK = cand[ci]; lgch = candl[ci]; break; }
  }
  unsigned* hbuf = (unsigned*)ws;  ws += (size_t)(CHUNK + 1) * 32768;
  char* zxp = ws;

  hipLaunchKernelGGL(k_cvt_embed, dim3(NV * ND / 4 / 256), dim3(256), 0, stream, embed, eb);
  hipLaunchKernelGGL(k_cvt_wi,    dim3(NH4 * ND / 256), dim3(256), 0, stream, wi, wit);
  hipLaunchKernelGGL(k_cvt_whp,   dim3(ND * NH4 / 256), dim3(256), 0, stream, wh, whp);

  for (int t0 = 0; t0 < NT; t0 += CHUNK) {
    hipLaunchKernelGGL(k_gemm_zx, dim3(CHUNK * 16), dim3(256), 0, stream,
                       tokens, eb, wit, zxp, t0, lgch);
    hipLaunchKernelGGL(k_poison, dim3(CHUNK * 32), dim3(256), 0, stream,
                       hbuf, CHUNK * 8192);
    hipLaunchKernelGGL(k_lstm, dim3(64), dim3(64), 0, stream,
                       zxp, whp, bh, cst, hst, hbuf, t0, CHUNK);
  }
  hipLaunchKernelGGL(k_out, dim3(NB), dim3(64), 0, stream, hst, wo, bo, y);
}